// Round 1
// baseline (461.963 us; speedup 1.0000x reference)
//
#include <hip/hip_runtime.h>
#include <hip/hip_bf16.h>

typedef __attribute__((ext_vector_type(8))) short short8;
typedef __attribute__((ext_vector_type(4))) float f32x4;

#define EPS 1e-5f

__device__ __forceinline__ unsigned short f2bf(float f) {
    union { float f; unsigned u; } v; v.f = f;
    unsigned u = v.u;
    u += 0x7FFFu + ((u >> 16) & 1u);   // RNE
    return (unsigned short)(u >> 16);
}
__device__ __forceinline__ float bflo(unsigned u) {
    union { unsigned u; float f; } v; v.u = u << 16; return v.f;
}
__device__ __forceinline__ float bfhi(unsigned u) {
    union { unsigned u; float f; } v; v.u = u & 0xffff0000u; return v.f;
}

// load 8 consecutive f32, convert to a bf16x8 MFMA fragment
__device__ __forceinline__ short8 load_frag_f32(const float* __restrict__ p) {
    f32x4 a = *(const f32x4*)p;
    f32x4 b = *(const f32x4*)(p + 4);
    short8 r;
    r[0] = (short)f2bf(a[0]); r[1] = (short)f2bf(a[1]);
    r[2] = (short)f2bf(a[2]); r[3] = (short)f2bf(a[3]);
    r[4] = (short)f2bf(b[0]); r[5] = (short)f2bf(b[1]);
    r[6] = (short)f2bf(b[2]); r[7] = (short)f2bf(b[3]);
    return r;
}

// ---------------- K1: qkv = x @ in_proj_w^T + b  (bf16 out) ----------------
// block = 256 thr (4 waves); block tile 64 rows x 384 cols; wave: 6 n-tiles x 4 m-tiles
__global__ __launch_bounds__(256) void k_qkv(
        const float* __restrict__ x, const float* __restrict__ w,
        const float* __restrict__ bias, ushort* __restrict__ qkv, int N) {
    const int wave = threadIdx.x >> 6, lane = threadIdx.x & 63;
    const int l16 = lane & 15, l4 = lane >> 4;
    const int base = blockIdx.x * 64;

    short8 af[4][4];
    #pragma unroll
    for (int mt = 0; mt < 4; ++mt) {
        int row = base + mt*16 + l16;
        int rc = row < N ? row : N - 1;
        const float* p = x + (size_t)rc*128 + l4*8;
        #pragma unroll
        for (int kb = 0; kb < 4; ++kb) af[mt][kb] = load_frag_f32(p + kb*32);
    }
    #pragma unroll
    for (int i = 0; i < 6; ++i) {
        int col = (wave*6 + i)*16 + l16;
        const float* pw = w + (size_t)col*128 + l4*8;
        short8 bf[4];
        #pragma unroll
        for (int kb = 0; kb < 4; ++kb) bf[kb] = load_frag_f32(pw + kb*32);
        float bv = bias[col];
        #pragma unroll
        for (int mt = 0; mt < 4; ++mt) {
            f32x4 acc = {0.f, 0.f, 0.f, 0.f};
            #pragma unroll
            for (int kb = 0; kb < 4; ++kb)
                acc = __builtin_amdgcn_mfma_f32_16x16x32_bf16(af[mt][kb], bf[kb], acc, 0, 0, 0);
            #pragma unroll
            for (int r = 0; r < 4; ++r) {
                int row = base + mt*16 + l4*4 + r;
                if (row < N) qkv[(size_t)row*384 + col] = f2bf(acc[r] + bv);
            }
        }
    }
}

// ---------------- K2: sampled attention -> ctx (bf16) ----------------
// one wave per node; lane = (k = lane&15, head-pair hp = lane>>4 -> heads hp, hp+4)
__global__ __launch_bounds__(256) void k_attn(
        const ushort* __restrict__ qkv, const int* __restrict__ samp,
        ushort* __restrict__ ctx, int N) {
    const int wave = threadIdx.x >> 6, lane = threadIdx.x & 63;
    const int n = blockIdx.x * 4 + wave;
    if (n >= N) return;
    const int k  = lane & 15;
    const int hp = lane >> 4;
    const int h0 = hp, h1 = hp + 4;

    const int idx = samp[(size_t)n*16 + k];
    const ushort* qrow = qkv + (size_t)n*384;
    const ushort* krow = qkv + (size_t)idx*384 + 128;
    const ushort* vrow = qkv + (size_t)idx*384 + 256;

    float s0 = 0.f, s1 = 0.f;
    {
        const unsigned* qa = (const unsigned*)(qrow + h0*16);
        const unsigned* ka = (const unsigned*)(krow + h0*16);
        const unsigned* qb = (const unsigned*)(qrow + h1*16);
        const unsigned* kb = (const unsigned*)(krow + h1*16);
        #pragma unroll
        for (int i = 0; i < 8; ++i) {
            unsigned ua = qa[i], va = ka[i], ub = qb[i], vb = kb[i];
            s0 += bflo(ua)*bflo(va) + bfhi(ua)*bfhi(va);
            s1 += bflo(ub)*bflo(vb) + bfhi(ub)*bfhi(vb);
        }
    }
    s0 *= 0.25f; s1 *= 0.25f;     // 1/sqrt(16)
    float m0 = s0, m1 = s1;
    #pragma unroll
    for (int off = 1; off < 16; off <<= 1) {
        m0 = fmaxf(m0, __shfl_xor(m0, off));
        m1 = fmaxf(m1, __shfl_xor(m1, off));
    }
    float e0 = __expf(s0 - m0), e1 = __expf(s1 - m1);
    float d0 = e0, d1 = e1;
    #pragma unroll
    for (int off = 1; off < 16; off <<= 1) {
        d0 += __shfl_xor(d0, off);
        d1 += __shfl_xor(d1, off);
    }
    float a0 = e0 / d0, a1 = e1 / d1;

    float p0[16], p1[16];
    {
        const unsigned* v0 = (const unsigned*)(vrow + h0*16);
        const unsigned* v1 = (const unsigned*)(vrow + h1*16);
        #pragma unroll
        for (int i = 0; i < 8; ++i) {
            unsigned ua = v0[i], ub = v1[i];
            p0[2*i]   = a0 * bflo(ua);
            p0[2*i+1] = a0 * bfhi(ua);
            p1[2*i]   = a1 * bflo(ub);
            p1[2*i+1] = a1 * bfhi(ub);
        }
    }
    #pragma unroll
    for (int off = 1; off < 16; off <<= 1) {
        #pragma unroll
        for (int d = 0; d < 16; ++d) {
            p0[d] += __shfl_xor(p0[d], off);
            p1[d] += __shfl_xor(p1[d], off);
        }
    }
    if (k == 0) {
        unsigned o[8];
        #pragma unroll
        for (int j = 0; j < 8; ++j)
            o[j] = (unsigned)f2bf(p0[2*j]) | ((unsigned)f2bf(p0[2*j+1]) << 16);
        uint4* dst0 = (uint4*)(ctx + (size_t)n*128 + h0*16);
        dst0[0] = make_uint4(o[0], o[1], o[2], o[3]);
        dst0[1] = make_uint4(o[4], o[5], o[6], o[7]);
        #pragma unroll
        for (int j = 0; j < 8; ++j)
            o[j] = (unsigned)f2bf(p1[2*j]) | ((unsigned)f2bf(p1[2*j+1]) << 16);
        uint4* dst1 = (uint4*)(ctx + (size_t)n*128 + h1*16);
        dst1[0] = make_uint4(o[0], o[1], o[2], o[3]);
        dst1[1] = make_uint4(o[4], o[5], o[6], o[7]);
    }
}

// ---------------- K3: y = LN1(x + ctx @ out_w^T + out_b) ----------------
// block 64 rows; wave = 1 m-tile (16 rows) x all 8 n-tiles -> full row in wave -> shuffle LN
__global__ __launch_bounds__(256) void k_oproj(
        const ushort* __restrict__ ctx, const float* __restrict__ ow,
        const float* __restrict__ ob, const float* __restrict__ x,
        const float* __restrict__ g1, const float* __restrict__ be1,
        float* __restrict__ y, int N) {
    const int wave = threadIdx.x >> 6, lane = threadIdx.x & 63;
    const int l16 = lane & 15, l4 = lane >> 4;
    const int mbase = blockIdx.x * 64 + wave * 16;

    short8 af[4];
    {
        int row = mbase + l16;
        int rc = row < N ? row : N - 1;
        const ushort* p = ctx + (size_t)rc*128 + l4*8;
        #pragma unroll
        for (int kb = 0; kb < 4; ++kb) af[kb] = *(const short8*)(p + kb*32);
    }
    f32x4 acc[8];
    #pragma unroll
    for (int nt = 0; nt < 8; ++nt) {
        int col = nt*16 + l16;
        const float* pw = ow + (size_t)col*128 + l4*8;
        f32x4 a = {0.f, 0.f, 0.f, 0.f};
        #pragma unroll
        for (int kb = 0; kb < 4; ++kb) {
            short8 bf = load_frag_f32(pw + kb*32);
            a = __builtin_amdgcn_mfma_f32_16x16x32_bf16(af[kb], bf, a, 0, 0, 0);
        }
        acc[nt] = a;
    }
    #pragma unroll
    for (int r = 0; r < 4; ++r) {
        int row = mbase + l4*4 + r;
        bool ok = row < N;
        int rc = ok ? row : N - 1;
        float s[8];
        float sum = 0.f, sq = 0.f;
        #pragma unroll
        for (int nt = 0; nt < 8; ++nt) {
            int col = nt*16 + l16;
            float v = acc[nt][r] + ob[col] + x[(size_t)rc*128 + col];
            s[nt] = v; sum += v; sq += v*v;
        }
        #pragma unroll
        for (int off = 1; off < 16; off <<= 1) {
            sum += __shfl_xor(sum, off);
            sq  += __shfl_xor(sq, off);
        }
        float mean = sum * (1.f/128.f);
        float rstd = rsqrtf(sq*(1.f/128.f) - mean*mean + EPS);
        if (ok) {
            #pragma unroll
            for (int nt = 0; nt < 8; ++nt) {
                int col = nt*16 + l16;
                y[(size_t)row*128 + col] = (s[nt]-mean)*rstd*g1[col] + be1[col];
            }
        }
    }
}

// ---------------- K4: out = LN2(y + relu(y@w1^T+b1)@w2^T + b2) ----------------
// block 64 rows. Stage1 -> h1 bf16 [64][512] in LDS (XOR-swizzled). Stage2 MFMA K=512.
// LN via f32 scratch aliasing h1 (after sync). out aliases y (row-local, safe).
__global__ __launch_bounds__(256) void k_ffn(
        const float* yin, const float* __restrict__ w1, const float* __restrict__ b1,
        const float* __restrict__ w2, const float* __restrict__ b2,
        const float* __restrict__ g2, const float* __restrict__ be2,
        float* out, int N) {
    __shared__ __align__(16) char smem[65536];
    float* sbuf = (float*)smem;                 // [64][132] f32 after stage2
    const int wave = threadIdx.x >> 6, lane = threadIdx.x & 63;
    const int l16 = lane & 15, l4 = lane >> 4;
    const int base = blockIdx.x * 64;

    // ---- stage 1 ----
    short8 af[4][4];
    #pragma unroll
    for (int mt = 0; mt < 4; ++mt) {
        int row = base + mt*16 + l16;
        int rc = row < N ? row : N - 1;
        const float* p = yin + (size_t)rc*128 + l4*8;
        #pragma unroll
        for (int kb = 0; kb < 4; ++kb) af[mt][kb] = load_frag_f32(p + kb*32);
    }
    #pragma unroll
    for (int i = 0; i < 8; ++i) {
        int col = (wave*8 + i)*16 + l16;
        const float* pw = w1 + (size_t)col*128 + l4*8;
        short8 bf[4];
        #pragma unroll
        for (int kb = 0; kb < 4; ++kb) bf[kb] = load_frag_f32(pw + kb*32);
        float bv = b1[col];
        #pragma unroll
        for (int mt = 0; mt < 4; ++mt) {
            f32x4 acc = {0.f, 0.f, 0.f, 0.f};
            #pragma unroll
            for (int kb = 0; kb < 4; ++kb)
                acc = __builtin_amdgcn_mfma_f32_16x16x32_bf16(af[mt][kb], bf[kb], acc, 0, 0, 0);
            #pragma unroll
            for (int r = 0; r < 4; ++r) {
                int row = mt*16 + l4*4 + r;        // row within tile
                float v = acc[r] + bv;
                v = v > 0.f ? v : 0.f;
                int byteoff = row*1024 + ((col*2) ^ ((row & 7) << 4));
                *(ushort*)(smem + byteoff) = f2bf(v);
            }
        }
    }
    __syncthreads();

    // ---- stage 2: wave handles n-tiles {2w, 2w+1} x 4 m-tiles, K=512 ----
    f32x4 acc2[4][2];
    #pragma unroll
    for (int mt = 0; mt < 4; ++mt)
        #pragma unroll
        for (int ntl = 0; ntl < 2; ++ntl) acc2[mt][ntl] = (f32x4){0.f,0.f,0.f,0.f};
    #pragma unroll 4
    for (int kb = 0; kb < 16; ++kb) {
        short8 a2[4];
        #pragma unroll
        for (int mt = 0; mt < 4; ++mt) {
            int row = mt*16 + l16;
            int kbyte = kb*64 + l4*16;
            a2[mt] = *(const short8*)(smem + row*1024 + (kbyte ^ ((row & 7) << 4)));
        }
        #pragma unroll
        for (int ntl = 0; ntl < 2; ++ntl) {
            int col = (wave*2 + ntl)*16 + l16;
            short8 bfr = load_frag_f32(w2 + (size_t)col*512 + kb*32 + l4*8);
            #pragma unroll
            for (int mt = 0; mt < 4; ++mt)
                acc2[mt][ntl] = __builtin_amdgcn_mfma_f32_16x16x32_bf16(a2[mt], bfr, acc2[mt][ntl], 0, 0, 0);
        }
    }
    __syncthreads();
    // ---- s = y + ff -> sbuf ----
    #pragma unroll
    for (int mt = 0; mt < 4; ++mt) {
        #pragma unroll
        for (int ntl = 0; ntl < 2; ++ntl) {
            int col = (wave*2 + ntl)*16 + l16;
            float bv = b2[col];
            #pragma unroll
            for (int r = 0; r < 4; ++r) {
                int row = mt*16 + l4*4 + r;
                int grow = base + row;
                int rc = grow < N ? grow : N - 1;
                sbuf[row*132 + col] = yin[(size_t)rc*128 + col] + acc2[mt][ntl][r] + bv;
            }
        }
    }
    __syncthreads();
    // ---- LN2: 4 threads per row ----
    {
        int row = threadIdx.x >> 2;     // 0..63
        int sub = threadIdx.x & 3;
        const float* sp = sbuf + row*132 + sub*32;
        float vals[32];
        float sum = 0.f, sq = 0.f;
        #pragma unroll
        for (int i = 0; i < 32; ++i) { float v = sp[i]; vals[i] = v; sum += v; sq += v*v; }
        sum += __shfl_xor(sum, 1); sq += __shfl_xor(sq, 1);
        sum += __shfl_xor(sum, 2); sq += __shfl_xor(sq, 2);
        float mean = sum * (1.f/128.f);
        float rstd = rsqrtf(sq*(1.f/128.f) - mean*mean + EPS);
        int grow = base + row;
        if (grow < N) {
            float* po = out + (size_t)grow*128 + sub*32;
            const float* pg = g2 + sub*32;
            const float* pb = be2 + sub*32;
            #pragma unroll
            for (int i = 0; i < 32; ++i)
                po[i] = (vals[i]-mean)*rstd*pg[i] + pb[i];
        }
    }
}

extern "C" void kernel_launch(void* const* d_in, const int* in_sizes, int n_in,
                              void* d_out, int out_size, void* d_ws, size_t ws_size,
                              hipStream_t stream) {
    (void)n_in; (void)out_size; (void)ws_size;
    const float* x   = (const float*)d_in[0];
    const int*   smp = (const int*)  d_in[1];
    const float* ipw = (const float*)d_in[2];
    const float* ipb = (const float*)d_in[3];
    const float* ow  = (const float*)d_in[4];
    const float* ob  = (const float*)d_in[5];
    const float* w1  = (const float*)d_in[6];
    const float* b1  = (const float*)d_in[7];
    const float* w2  = (const float*)d_in[8];
    const float* b2  = (const float*)d_in[9];
    const float* g1  = (const float*)d_in[10];
    const float* be1 = (const float*)d_in[11];
    const float* g2  = (const float*)d_in[12];
    const float* be2 = (const float*)d_in[13];
    const int N = in_sizes[0] / 128;

    ushort* qkv = (ushort*)d_ws;                    // [N][384] bf16
    ushort* ctx = qkv + (size_t)N * 384;            // [N][128] bf16
    float*  y   = (float*)d_out;                    // staged y, then final out

    const int nb = (N + 63) / 64;
    k_qkv  <<<nb,        256, 0, stream>>>(x, ipw, ipb, qkv, N);
    k_attn <<<(N+3)/4,   256, 0, stream>>>(qkv, smp, ctx, N);
    k_oproj<<<nb,        256, 0, stream>>>(ctx, ow, ob, x, g1, be1, y, N);
    k_ffn  <<<nb,        256, 0, stream>>>(y, w1, b1, w2, b2, g2, be2, y, N);
}